// Round 4
// baseline (771.462 us; speedup 1.0000x reference)
//
#include <hip/hip_runtime.h>

// Problem constants
#define TOTAL_DIM 24976   // 400 + 60*256 + 36*256
#define N_ROWS    97      // 1 + 60 + 36
#define D_MODEL   512
#define EPSLN     1e-5f

// Wt (bf16, MFMA-FRAGMENT-order, k-padded) layout in d_ws (elem = bf16):
//  per split: frag f = nt_g*NSTEP + t holds 512 elems: [lane 0..63][j 0..7]
//   value = W^T[n = nt_g*16 + (lane&15)][k = t*32 + (lane>>4)*8 + j]
//  split0: NSTEP=13 (KP=416), base elem 0        (32*13*512 = 212992)
//  split1: NSTEP=8  (KP=256), base elem 212992   (32*8*512  = 131072)
//  split2: NSTEP=8  (KP=256), base elem 344064   (131072)
#define WT_TOTAL 475136
#define WT_BYTES (WT_TOTAL * 2)

// dynamic LDS: persistent path A 16384 + red 4096 + stat 256 = 20736
//              S0 leg        A 26624 + red 4096 + stat 256 = 30976 (disjoint offsets)
#define SMEM_FUSED 30976

typedef __attribute__((ext_vector_type(8))) short frag8;   // 8 bf16 = 4 VGPRs
typedef __attribute__((ext_vector_type(4))) float frag4;   // 4 fp32 acc

__device__ __forceinline__ unsigned short f2b(float f) {
  // fp32 -> bf16 round-to-nearest-even
  unsigned u = __float_as_uint(f);
  u = u + 0x7fffu + ((u >> 16) & 1u);
  return (unsigned short)(u >> 16);
}

__device__ __forceinline__ unsigned cvt2bf(float lo, float hi) {
  // packs 2 fp32 -> 2 bf16 (RNE), single instruction; same rounding as f2b
  unsigned r;
  asm("v_cvt_pk_bf16_f32 %0, %1, %2" : "=v"(r) : "v"(lo), "v"(hi));
  return r;
}

// ---------------- prep: W fp32 [l][512] -> bf16 W^T in MFMA-fragment order ------
// one thread per uint2 (4 bf16). 464 blocks * 256 = 118784 = WT_TOTAL/4 threads.
__global__ void __launch_bounds__(256) prep_wt(const float* __restrict__ W0,
                                               const float* __restrict__ W1,
                                               const float* __restrict__ W2,
                                               unsigned short* __restrict__ wt) {
  int i = blockIdx.x * 256 + threadIdx.x;   // uint2 index, 0..118783
  if (i >= WT_TOTAL / 4) return;
  const float* W; int L, NSTEP, u;
  if (i < 53248)      { W = W0; L = 400; NSTEP = 13; u = i; }
  else if (i < 86016) { W = W1; L = 256; NSTEP = 8;  u = i - 53248; }
  else                { W = W2; L = 256; NSTEP = 8;  u = i - 86016; }
  int j4 = u & 1;                 // which 4-element half of the lane's 8
  int l  = (u >> 1) & 63;         // lane
  int fi = u >> 7;                // frag index = nt_g*NSTEP + t
  int t  = fi % NSTEP;
  int nt = fi / NSTEP;
  int n  = nt * 16 + (l & 15);
  int k0 = t * 32 + (l >> 4) * 8 + j4 * 4;
  float v[4];
#pragma unroll
  for (int j = 0; j < 4; ++j) {
    int k = k0 + j;
    v[j] = (k < L) ? W[k * 512 + n] : 0.f;   // zero-pad k >= L
  }
  unsigned lo = (unsigned)f2b(v[0]) | ((unsigned)f2b(v[1]) << 16);
  unsigned hi = (unsigned)f2b(v[2]) | ((unsigned)f2b(v[3]) << 16);
  ((uint2*)wt)[i] = make_uint2(lo, hi);
}

// ---------------- shared epilogue: bias + ReLU + LayerNorm + store ---------------
// 32-row tile, acc[2][2]; C/D layout: col = lane&15 (c), row = q*4 + reg [m89]
template <int KK, int OFF>
__device__ __forceinline__ void epilogue32(
    frag4 (&acc)[2][2], int m_base, int w, int q, int c, int tid, int colbase,
    const float (&bv)[2], const float (&gv)[2], const float (&ev)[2],
    float* red, float* stat, float* __restrict__ out) {
#pragma unroll
  for (int mt = 0; mt < 2; ++mt) {
    float s[4] = {0.f, 0.f, 0.f, 0.f}, s2[4] = {0.f, 0.f, 0.f, 0.f};
#pragma unroll
    for (int nt = 0; nt < 2; ++nt)
#pragma unroll
      for (int r = 0; r < 4; ++r) {
        float h = acc[mt][nt][r] + bv[nt];
        h = fmaxf(h, 0.f);
        acc[mt][nt][r] = h;
        s[r] += h;
        s2[r] += h * h;
      }
#pragma unroll
    for (int r = 0; r < 4; ++r) {
      float a = s[r], b2 = s2[r];
#pragma unroll
      for (int msk = 1; msk < 16; msk <<= 1) {  // reduce 16 cols (same q group)
        a += __shfl_xor(a, msk, 64);
        b2 += __shfl_xor(b2, msk, 64);
      }
      if (c == 0) {
        int row = mt * 16 + q * 4 + r;
        red[(w * 32 + row) * 2 + 0] = a;
        red[(w * 32 + row) * 2 + 1] = b2;
      }
    }
  }
  __syncthreads();   // also publishes this iteration's A-slab ds_writes
  if (tid < 32) {
    float s = 0.f, s2 = 0.f;
#pragma unroll
    for (int ww = 0; ww < 16; ++ww) {
      s  += red[(ww * 32 + tid) * 2 + 0];
      s2 += red[(ww * 32 + tid) * 2 + 1];
    }
    float mu  = s * (1.f / 512.f);
    float var = s2 * (1.f / 512.f) - mu * mu;
    stat[tid * 2 + 0] = mu;
    stat[tid * 2 + 1] = rsqrtf(var + EPSLN);
  }
  __syncthreads();
#pragma unroll
  for (int mt = 0; mt < 2; ++mt)
#pragma unroll
    for (int r = 0; r < 4; ++r) {
      int row = mt * 16 + q * 4 + r;
      float mu = stat[row * 2 + 0], sc = stat[row * 2 + 1];
      int m = m_base + row;
      int bb = m / KK, jj = m - bb * KK;   // const divisor -> magic mul
      size_t orow = (size_t)bb * N_ROWS + OFF + jj;
      float* op = out + orow * D_MODEL + colbase;
#pragma unroll
      for (int nt = 0; nt < 2; ++nt)
        op[nt * 16] = (acc[mt][nt][r] - mu) * sc * gv[nt] + ev[nt];
    }
}

// ---------------- persistent path: S in {1,2}, 24 tiles of 32 rows x 512 cols ----
// B frags (16 = 64 VGPR) loaded ONCE per block; K-loop is pure ds_read+MFMA with
// zero barriers/globals. Next tile's A issued before K-loop (T14), written after.
template <int S>
__device__ __forceinline__ void run_persistent(
    int tile0, int ntiles, char* smem,
    const float* __restrict__ x, const unsigned short* __restrict__ wt,
    const float* __restrict__ bias, const float* __restrict__ gam,
    const float* __restrict__ bet, float* __restrict__ out) {
  constexpr int L     = 256, NSTEP = 8;
  constexpr int START = (S == 1) ? 400 : 15760;
  constexpr int KK    = (S == 1) ? 60 : 36;
  constexpr int OFF   = (S == 1) ? 1 : 61;
  constexpr int WTO   = (S == 1) ? 212992 : 344064;
  constexpr int RS    = 512;                 // bf16 A row stride (bytes)

  unsigned short* A = (unsigned short*)smem;           // [32][256] bf16, swizzled
  float* red  = (float*)(smem + 16384);                // [16][32][2]
  float* stat = (float*)(smem + 20480);                // [32][2]

  const int tid = threadIdx.x, lane = tid & 63, w = tid >> 6;
  const int q = lane >> 4, c = lane & 15;
  const int sr = tid >> 5, sch = tid & 31;             // staging: row, chunk lane
  const int swr = (sr & 7) << 4;                       // write-side swizzle
  const int sw  = (c & 7) << 4;                        // read-side swizzle

  // ---- B fragments: resident for whole block (cols fixed across tiles)
  frag8 bc[NSTEP][2];
#pragma unroll
  for (int nt = 0; nt < 2; ++nt)
#pragma unroll
    for (int t = 0; t < NSTEP; ++t)
      bc[t][nt] = *(const frag8*)(wt + WTO + ((2 * w + nt) * NSTEP + t) * 512 + lane * 8);

  const int colbase = w * 32 + c;
  float bv[2], gv[2], ev[2];
#pragma unroll
  for (int nt = 0; nt < 2; ++nt) {
    bv[nt] = bias[colbase + nt * 16];
    gv[nt] = gam[colbase + nt * 16];
    ev[nt] = bet[colbase + nt * 16];
  }

  // ---- stage tile0 (32 rows x 256 fp32 = 2 float4/thread)
  float4 st0, st1;
  {
    int m = tile0 * 32 + sr;
    int bb = m / KK, jj = m - bb * KK;
    const float* rp = x + (size_t)bb * TOTAL_DIM + START + (size_t)jj * L + sch * 4;
    st0 = *(const float4*)rp;
    st1 = *(const float4*)(rp + 128);
  }
  {
    *(uint2*)((char*)A + sr * RS + ((sch * 8) ^ swr)) =
        make_uint2(cvt2bf(st0.x, st0.y), cvt2bf(st0.z, st0.w));
    *(uint2*)((char*)A + sr * RS + ((sch * 8 + 256) ^ swr)) =
        make_uint2(cvt2bf(st1.x, st1.y), cvt2bf(st1.z, st1.w));
  }
  __syncthreads();

  for (int i = 0; i < ntiles; ++i) {
    const int m_base = (tile0 + i) * 32;
    const bool more = (i + 1 < ntiles);
    if (more) {   // issue next tile's loads NOW; latency hides under K-loop
      int m = m_base + 32 + sr;
      int bb = m / KK, jj = m - bb * KK;
      const float* rp = x + (size_t)bb * TOTAL_DIM + START + (size_t)jj * L + sch * 4;
      st0 = *(const float4*)rp;
      st1 = *(const float4*)(rp + 128);
    }

    frag4 acc[2][2];
#pragma unroll
    for (int mt = 0; mt < 2; ++mt)
#pragma unroll
      for (int nt = 0; nt < 2; ++nt) {
        frag4 z = {0.f, 0.f, 0.f, 0.f};
        acc[mt][nt] = z;
      }

    // ---- K loop: pure LDS + MFMA, no barriers, no global loads
#pragma unroll
    for (int t = 0; t < NSTEP; ++t) {
      const int off = (t * 64 + q * 16) ^ sw;
      frag8 a0 = *(const frag8*)((char*)A + (c) * RS + off);
      frag8 a1 = *(const frag8*)((char*)A + (16 + c) * RS + off);
      acc[0][0] = __builtin_amdgcn_mfma_f32_16x16x32_bf16(a0, bc[t][0], acc[0][0], 0, 0, 0);
      acc[0][1] = __builtin_amdgcn_mfma_f32_16x16x32_bf16(a0, bc[t][1], acc[0][1], 0, 0, 0);
      acc[1][0] = __builtin_amdgcn_mfma_f32_16x16x32_bf16(a1, bc[t][0], acc[1][0], 0, 0, 0);
      acc[1][1] = __builtin_amdgcn_mfma_f32_16x16x32_bf16(a1, bc[t][1], acc[1][1], 0, 0, 0);
    }
    __syncthreads();   // all K-loop reads done -> safe to overwrite A slab
    if (more) {        // write-late half of the staging split
      *(uint2*)((char*)A + sr * RS + ((sch * 8) ^ swr)) =
          make_uint2(cvt2bf(st0.x, st0.y), cvt2bf(st0.z, st0.w));
      *(uint2*)((char*)A + sr * RS + ((sch * 8 + 256) ^ swr)) =
          make_uint2(cvt2bf(st1.x, st1.y), cvt2bf(st1.z, st1.w));
    }
    epilogue32<KK, OFF>(acc, m_base, w, q, c, tid, colbase, bv, gv, ev,
                        red, stat, out);
  }
}

// ---------------- S0 leg: one 32-row tile, KP=416, in-loop B prefetch ------------
__device__ __forceinline__ void run_s0(
    int tile, char* smem,
    const float* __restrict__ x, const unsigned short* __restrict__ wt,
    const float* __restrict__ bias, const float* __restrict__ gam,
    const float* __restrict__ bet, float* __restrict__ out) {
  constexpr int L = 400, NSTEP = 13, RS = 832;   // 416 bf16 per row

  unsigned short* A = (unsigned short*)smem;     // [32][416] bf16, no swizzle
  float* red  = (float*)(smem + 26624);
  float* stat = (float*)(smem + 30720);

  const int tid = threadIdx.x, lane = tid & 63, w = tid >> 6;
  const int q = lane >> 4, c = lane & 15;
  const int sr = tid >> 5, sch = tid & 31;

  const unsigned short* bp0 = wt + (2 * w) * (NSTEP * 512) + lane * 8;
  const unsigned short* bp1 = bp0 + NSTEP * 512;
  frag8 bc0 = *(const frag8*)bp0;
  frag8 bc1 = *(const frag8*)bp1;

  // stage: 32 rows x 416 (=KP) fp32-chunks; 4 passes of 32 chunks
  {
    int m = tile * 32 + sr;                       // KK=1: bb=m, jj=0
    const float* rp = x + (size_t)m * TOTAL_DIM;
#pragma unroll
    for (int p = 0; p < 4; ++p) {
      int c4 = sch + p * 32;
      if (c4 >= 104) continue;
      float4 v;
      if (c4 >= 100) { v.x = 0.f; v.y = 0.f; v.z = 0.f; v.w = 0.f; }  // pad 400..415
      else           { v = *(const float4*)(rp + c4 * 4); }
      *(uint2*)((char*)A + sr * RS + c4 * 8) =
          make_uint2(cvt2bf(v.x, v.y), cvt2bf(v.z, v.w));
    }
  }

  const int colbase = w * 32 + c;
  float bv[2], gv[2], ev[2];
#pragma unroll
  for (int nt = 0; nt < 2; ++nt) {
    bv[nt] = bias[colbase + nt * 16];
    gv[nt] = gam[colbase + nt * 16];
    ev[nt] = bet[colbase + nt * 16];
  }

  frag4 acc[2][2];
#pragma unroll
  for (int mt = 0; mt < 2; ++mt)
#pragma unroll
    for (int nt = 0; nt < 2; ++nt) {
      frag4 z = {0.f, 0.f, 0.f, 0.f};
      acc[mt][nt] = z;
    }
  __syncthreads();

#pragma unroll
  for (int t = 0; t < NSTEP; ++t) {
    frag8 bn0, bn1;
    const bool pre = (t + 1 < NSTEP);
    if (pre) {
      bn0 = *(const frag8*)(bp0 + (t + 1) * 512);
      bn1 = *(const frag8*)(bp1 + (t + 1) * 512);
    }
    const int off = t * 64 + q * 16;
    frag8 a0 = *(const frag8*)((char*)A + (c) * RS + off);
    frag8 a1 = *(const frag8*)((char*)A + (16 + c) * RS + off);
    acc[0][0] = __builtin_amdgcn_mfma_f32_16x16x32_bf16(a0, bc0, acc[0][0], 0, 0, 0);
    acc[0][1] = __builtin_amdgcn_mfma_f32_16x16x32_bf16(a0, bc1, acc[0][1], 0, 0, 0);
    acc[1][0] = __builtin_amdgcn_mfma_f32_16x16x32_bf16(a1, bc0, acc[1][0], 0, 0, 0);
    acc[1][1] = __builtin_amdgcn_mfma_f32_16x16x32_bf16(a1, bc1, acc[1][1], 0, 0, 0);
    if (pre) { bc0 = bn0; bc1 = bn1; }
  }
  __syncthreads();   // K-loop done before epilogue reuses red/stat region
  epilogue32<1, 0>(acc, tile * 32, w, q, c, tid, colbase, bv, gv, ev,
                   red, stat, out);
}

// ---------------- persistent fused kernel: grid = 256 = #CUs ---------------------
// blocks [0,160): split1, 24 tiles each (160*24*32 = 122880 rows)
// blocks [160,256): split2, 24 tiles each (96*24*32 = 73728 rows);
//   blocks [160,224) first run one split0 tile (64*32 = 2048 rows)
__global__ void __launch_bounds__(1024, 4) fused_kernel(
    const float* __restrict__ x, const unsigned short* __restrict__ wt,
    const float* __restrict__ b0, const float* __restrict__ g0, const float* __restrict__ e0,
    const float* __restrict__ b1, const float* __restrict__ g1, const float* __restrict__ e1,
    const float* __restrict__ b2, const float* __restrict__ g2, const float* __restrict__ e2,
    float* __restrict__ out) {
  extern __shared__ char smem[];
  int b = blockIdx.x;
  if (b < 160) {
    run_persistent<1>(b * 24, 24, smem, x, wt, b1, g1, e1, out);
  } else {
    int s2b = b - 160;
    if (s2b < 64) run_s0(s2b, smem, x, wt, b0, g0, e0, out);
    run_persistent<2>(s2b * 24, 24, smem, x, wt, b2, g2, e2, out);
  }
}

// ---------------- fallback: fp32 vector path, zero workspace ---------------------
// one block = one output row. Correct-but-slow; only used if ws_size is too small.
template <int S>
__global__ void __launch_bounds__(256) fallback_split(
    const float* __restrict__ x, const float* __restrict__ W,
    const float* __restrict__ bias, const float* __restrict__ gam,
    const float* __restrict__ bet, float* __restrict__ out) {
  constexpr int L     = (S == 0) ? 400 : 256;
  constexpr int START = (S == 0) ? 0 : (S == 1) ? 400 : 15760;
  constexpr int KK    = (S == 0) ? 1 : (S == 1) ? 60 : 36;
  constexpr int OFF   = (S == 0) ? 0 : (S == 1) ? 1 : 61;

  __shared__ float xs[400];
  __shared__ float rs[4], rs2[4];

  int m = blockIdx.x;
  int bb = m / KK, jj = m - bb * KK;
  const float* xp = x + (size_t)bb * TOTAL_DIM + START + jj * L;
  for (int k = threadIdx.x; k < L; k += 256) xs[k] = xp[k];
  __syncthreads();

  float h[2];
#pragma unroll
  for (int i = 0; i < 2; ++i) {
    int col = threadIdx.x + i * 256;
    float acc = 0.f;
    for (int k = 0; k < L; ++k) acc += xs[k] * W[k * 512 + col];
    h[i] = fmaxf(acc + bias[col], 0.f);
  }

  float s = h[0] + h[1], s2 = h[0] * h[0] + h[1] * h[1];
#pragma unroll
  for (int msk = 1; msk < 64; msk <<= 1) {
    s  += __shfl_xor(s, msk, 64);
    s2 += __shfl_xor(s2, msk, 64);
  }
  int wave = threadIdx.x >> 6, lane = threadIdx.x & 63;
  if (lane == 0) { rs[wave] = s; rs2[wave] = s2; }
  __syncthreads();
  s  = rs[0] + rs[1] + rs[2] + rs[3];
  s2 = rs2[0] + rs2[1] + rs2[2] + rs2[3];
  float mu  = s * (1.f / 512.f);
  float var = s2 * (1.f / 512.f) - mu * mu;
  float sc  = rsqrtf(var + EPSLN);

  float* op = out + ((size_t)bb * N_ROWS + OFF + jj) * D_MODEL;
#pragma unroll
  for (int i = 0; i < 2; ++i) {
    int col = threadIdx.x + i * 256;
    op[col] = (h[i] - mu) * sc * gam[col] + bet[col];
  }
}

extern "C" void kernel_launch(void* const* d_in, const int* in_sizes, int n_in,
                              void* d_out, int out_size, void* d_ws, size_t ws_size,
                              hipStream_t stream) {
  const float* x  = (const float*)d_in[0];
  const float* W0 = (const float*)d_in[1];
  const float* b0 = (const float*)d_in[2];
  const float* g0 = (const float*)d_in[3];
  const float* e0 = (const float*)d_in[4];
  const float* W1 = (const float*)d_in[5];
  const float* b1 = (const float*)d_in[6];
  const float* g1 = (const float*)d_in[7];
  const float* e1 = (const float*)d_in[8];
  const float* W2 = (const float*)d_in[9];
  const float* b2 = (const float*)d_in[10];
  const float* g2 = (const float*)d_in[11];
  const float* e2 = (const float*)d_in[12];
  float* out = (float*)d_out;

  if (ws_size >= (size_t)WT_BYTES) {
    // fast path: bf16 MFMA, persistent fused GEMM+bias+ReLU+LN
    unsigned short* wt = (unsigned short*)d_ws;
    prep_wt<<<464, 256, 0, stream>>>(W0, W1, W2, wt);
    fused_kernel<<<256, 1024, SMEM_FUSED, stream>>>(
        x, wt, b0, g0, e0, b1, g1, e1, b2, g2, e2, out);
  } else {
    // zero-workspace fp32 fallback (correct, slower)
    fallback_split<0><<<2048,   256, 0, stream>>>(x, W0, b0, g0, e0, out);
    fallback_split<1><<<122880, 256, 0, stream>>>(x, W1, b1, g1, e1, out);
    fallback_split<2><<<73728,  256, 0, stream>>>(x, W2, b2, g2, e2, out);
  }
}

// Round 5
// 639.118 us; speedup vs baseline: 1.2071x; 1.2071x over previous
//
#include <hip/hip_runtime.h>

// Problem constants
#define TOTAL_DIM 24976   // 400 + 60*256 + 36*256
#define N_ROWS    97      // 1 + 60 + 36
#define D_MODEL   512
#define EPSLN     1e-5f

// grid: 16 output rows per 512-thread workgroup; 4 blocks/CU (VGPR<=64)
#define NB0 128    // 2048/16
#define NB1 7680   // 122880/16
#define NB2 4608   // 73728/16

// Wt (bf16, MFMA-FRAGMENT-order, k-padded) layout in d_ws (elem = bf16):
//  per split: frag f = nt_g*NSTEP + t holds 512 elems: [lane 0..63][j 0..7]
//   value = W^T[n = nt_g*16 + (lane&15)][k = t*32 + (lane>>4)*8 + j]
//  split0: NSTEP=13 (KP=416), base elem 0        (32*13*512 = 212992)
//  split1: NSTEP=8  (KP=256), base elem 212992   (32*8*512  = 131072)
//  split2: NSTEP=8  (KP=256), base elem 344064   (131072)
#define WT_TOTAL 475136
#define WT_BYTES (WT_TOTAL * 2)

// dynamic LDS: worst case S0: A 16*832=13312 + red 1024 + stat 128 = 14464
#define SMEM_FUSED 14464

typedef __attribute__((ext_vector_type(8))) short frag8;   // 8 bf16 = 4 VGPRs
typedef __attribute__((ext_vector_type(4))) float frag4;   // 4 fp32 acc

__device__ __forceinline__ unsigned short f2b(float f) {
  // fp32 -> bf16 round-to-nearest-even
  unsigned u = __float_as_uint(f);
  u = u + 0x7fffu + ((u >> 16) & 1u);
  return (unsigned short)(u >> 16);
}

__device__ __forceinline__ unsigned cvt2bf(float lo, float hi) {
  // packs 2 fp32 -> 2 bf16 (RNE), single instruction; same rounding as f2b
  unsigned r;
  asm("v_cvt_pk_bf16_f32 %0, %1, %2" : "=v"(r) : "v"(lo), "v"(hi));
  return r;
}

// ---------------- prep: W fp32 [l][512] -> bf16 W^T in MFMA-fragment order ------
// one thread per uint2 (4 bf16). 464 blocks * 256 = 118784 = WT_TOTAL/4 threads.
__global__ void __launch_bounds__(256) prep_wt(const float* __restrict__ W0,
                                               const float* __restrict__ W1,
                                               const float* __restrict__ W2,
                                               unsigned short* __restrict__ wt) {
  int i = blockIdx.x * 256 + threadIdx.x;   // uint2 index, 0..118783
  if (i >= WT_TOTAL / 4) return;
  const float* W; int L, NSTEP, u;
  if (i < 53248)      { W = W0; L = 400; NSTEP = 13; u = i; }
  else if (i < 86016) { W = W1; L = 256; NSTEP = 8;  u = i - 53248; }
  else                { W = W2; L = 256; NSTEP = 8;  u = i - 86016; }
  int j4 = u & 1;                 // which 4-element half of the lane's 8
  int l  = (u >> 1) & 63;         // lane
  int fi = u >> 7;                // frag index = nt_g*NSTEP + t
  int t  = fi % NSTEP;
  int nt = fi / NSTEP;
  int n  = nt * 16 + (l & 15);
  int k0 = t * 32 + (l >> 4) * 8 + j4 * 4;
  float v[4];
#pragma unroll
  for (int j = 0; j < 4; ++j) {
    int k = k0 + j;
    v[j] = (k < L) ? W[k * 512 + n] : 0.f;   // zero-pad k >= L
  }
  unsigned lo = (unsigned)f2b(v[0]) | ((unsigned)f2b(v[1]) << 16);
  unsigned hi = (unsigned)f2b(v[2]) | ((unsigned)f2b(v[3]) << 16);
  ((uint2*)wt)[i] = make_uint2(lo, hi);
}

// ---------------- fused GEMM + bias + ReLU + LayerNorm ---------------------------
// one workgroup = 16 rows x 512 cols (full N -> LN workgroup-local), 512 threads.
// wave w owns 16 rows x 64 cols (nt_g = 4w..4w+3): acc = 4 x frag4 = 16 VGPRs.
// B frags load coalesced (512B/wave) from fragment-order wt (L2-resident);
// compiler hoists them across the unrolled K loop within the 64-VGPR budget.
// 4 independent blocks/CU keep memory phases decorrelated (the round-3/4
// lesson: big barrier-coupled blocks leave all pipes idle at barriers).
template <int S>
__device__ __forceinline__ void run16(
    int blk, char* smem,
    const float* __restrict__ x, const unsigned short* __restrict__ wt,
    const float* __restrict__ bias, const float* __restrict__ gam,
    const float* __restrict__ bet, float* __restrict__ out) {
  constexpr int L     = (S == 0) ? 400 : 256;       // true K
  constexpr int KP    = (S == 0) ? 416 : 256;       // padded K (mult of 32)
  constexpr int NSTEP = KP / 32;
  constexpr int START = (S == 0) ? 0 : (S == 1) ? 400 : 15760;
  constexpr int KK    = (S == 0) ? 1 : (S == 1) ? 60 : 36;   // slices per batch row
  constexpr int OFF   = (S == 0) ? 0 : (S == 1) ? 1 : 61;    // row offset in output
  constexpr int WTO   = (S == 0) ? 0 : (S == 1) ? 212992 : 344064;
  constexpr int RS    = KP * 2;                     // LDS A row stride (bytes)
  // XOR swizzle needs row granule count (KP/8) to be a multiple of 8:
  // split1/2: 32 ok; split0: 52 -> skip (832B stride 2-way on c-pairs, 1% of work)
  constexpr bool SWZ  = (S != 0);

  unsigned short* A = (unsigned short*)smem;                 // [16][KP] bf16
  float* red  = (float*)(smem + 16 * RS);                    // [16 rows][8 waves][2]
  float* stat = (float*)(smem + 16 * RS + 1024);             // [16][2]

  const int tid = threadIdx.x, lane = tid & 63, w = tid >> 6;
  const int q = lane >> 4, c = lane & 15;
  const int m_base = blk * 16;

  // ---- A staging: 16 rows, 32 threads/row, coalesced fp32 -> bf16 -> LDS
  {
    int sr = tid >> 5, sch = tid & 31;
    int m = m_base + sr;
    int bb = m / KK, jj = m - bb * KK;     // const divisor -> magic mul
    const float* rp = x + (size_t)bb * TOTAL_DIM + START + (size_t)jj * L;
    if (S == 0) {
      // 104 uint2 positions per row (KP=416), 32 threads -> 4 passes
#pragma unroll
      for (int p = 0; p < 4; ++p) {
        int c4 = sch + p * 32;
        if (c4 >= 104) continue;
        float4 v;
        if (c4 >= 100) { v.x = 0.f; v.y = 0.f; v.z = 0.f; v.w = 0.f; }  // pad 400..415
        else           { v = *(const float4*)(rp + c4 * 4); }
        *(uint2*)((char*)A + sr * RS + c4 * 8) =
            make_uint2(cvt2bf(v.x, v.y), cvt2bf(v.z, v.w));
      }
    } else {
      const int swr = (sr & 7) << 4;       // write-side swizzle
      float4 v0 = *(const float4*)(rp + sch * 4);
      float4 v1 = *(const float4*)(rp + sch * 4 + 128);
      *(uint2*)((char*)A + sr * RS + ((sch * 8) ^ swr)) =
          make_uint2(cvt2bf(v0.x, v0.y), cvt2bf(v0.z, v0.w));
      *(uint2*)((char*)A + sr * RS + ((sch * 8 + 256) ^ swr)) =
          make_uint2(cvt2bf(v1.x, v1.y), cvt2bf(v1.z, v1.w));
    }
  }

  frag4 acc[4];
#pragma unroll
  for (int nt = 0; nt < 4; ++nt) {
    frag4 z = {0.f, 0.f, 0.f, 0.f};
    acc[nt] = z;
  }

  __syncthreads();   // A slab ready

  const int sw = SWZ ? ((c & 7) << 4) : 0;     // read-side swizzle
  const unsigned short* bbase = wt + WTO + (w * 4) * (NSTEP * 512) + lane * 8;

  // ---- K loop: A from LDS (2-way, free), B coalesced from L2-resident wt
#pragma unroll
  for (int t = 0; t < NSTEP; ++t) {
    frag8 af = *(const frag8*)((char*)A + c * RS + ((t * 64 + q * 16) ^ sw));
#pragma unroll
    for (int nt = 0; nt < 4; ++nt) {
      frag8 bf = *(const frag8*)(bbase + (nt * NSTEP + t) * 512);
      acc[nt] = __builtin_amdgcn_mfma_f32_16x16x32_bf16(af, bf, acc[nt], 0, 0, 0);
    }
  }

  // ---- epilogue: bias + ReLU + LayerNorm, from registers
  const int colbase = w * 64 + c;
  float bv[4], gv[4], ev[4];
#pragma unroll
  for (int nt = 0; nt < 4; ++nt) {
    int col = colbase + nt * 16;
    bv[nt] = bias[col];
    gv[nt] = gam[col];
    ev[nt] = bet[col];
  }

  // C/D layout: col = lane&15 (c), row = q*4 + reg  [m89-verified]
  float s[4] = {0.f, 0.f, 0.f, 0.f}, s2[4] = {0.f, 0.f, 0.f, 0.f};
#pragma unroll
  for (int nt = 0; nt < 4; ++nt)
#pragma unroll
    for (int r = 0; r < 4; ++r) {
      float h = acc[nt][r] + bv[nt];
      h = fmaxf(h, 0.f);
      acc[nt][r] = h;
      s[r] += h;
      s2[r] += h * h;
    }
#pragma unroll
  for (int r = 0; r < 4; ++r) {
    float a = s[r], b2 = s2[r];
#pragma unroll
    for (int msk = 1; msk < 16; msk <<= 1) {  // reduce 16 cols (same q group)
      a += __shfl_xor(a, msk, 64);
      b2 += __shfl_xor(b2, msk, 64);
    }
    if (c == 0) {
      int row = q * 4 + r;
      red[(row * 8 + w) * 2 + 0] = a;
      red[(row * 8 + w) * 2 + 1] = b2;
    }
  }
  __syncthreads();
  if (tid < 16) {   // per row: 8 contiguous float2 = 64B, then reduce
    float s0 = 0.f, s20 = 0.f;
#pragma unroll
    for (int ww = 0; ww < 8; ++ww) {
      s0  += red[(tid * 8 + ww) * 2 + 0];
      s20 += red[(tid * 8 + ww) * 2 + 1];
    }
    float mu  = s0 * (1.f / 512.f);
    float var = s20 * (1.f / 512.f) - mu * mu;
    stat[tid * 2 + 0] = mu;
    stat[tid * 2 + 1] = rsqrtf(var + EPSLN);
  }
  __syncthreads();

#pragma unroll
  for (int r = 0; r < 4; ++r) {
    int row = q * 4 + r;
    float mu = stat[row * 2 + 0], sc = stat[row * 2 + 1];
    int m = m_base + row;
    int bb = m / KK, jj = m - bb * KK;   // const divisor -> magic mul
    size_t orow = (size_t)bb * N_ROWS + OFF + jj;
    float* op = out + orow * D_MODEL + colbase;
#pragma unroll
    for (int nt = 0; nt < 4; ++nt)
      op[nt * 16] = (acc[nt][r] - mu) * sc * gv[nt] + ev[nt];
  }
}

__global__ void __launch_bounds__(512, 8) fused_kernel(
    const float* __restrict__ x, const unsigned short* __restrict__ wt,
    const float* __restrict__ b0, const float* __restrict__ g0, const float* __restrict__ e0,
    const float* __restrict__ b1, const float* __restrict__ g1, const float* __restrict__ e1,
    const float* __restrict__ b2, const float* __restrict__ g2, const float* __restrict__ e2,
    float* __restrict__ out) {
  extern __shared__ char smem[];
  int bid = blockIdx.x;
  if (bid < NB0)
    run16<0>(bid, smem, x, wt, b0, g0, e0, out);           // longest K first
  else if (bid < NB0 + NB1)
    run16<1>(bid - NB0, smem, x, wt, b1, g1, e1, out);
  else
    run16<2>(bid - NB0 - NB1, smem, x, wt, b2, g2, e2, out);
}

// ---------------- fallback: fp32 vector path, zero workspace ---------------------
// one block = one output row. Correct-but-slow; only used if ws_size is too small.
template <int S>
__global__ void __launch_bounds__(256) fallback_split(
    const float* __restrict__ x, const float* __restrict__ W,
    const float* __restrict__ bias, const float* __restrict__ gam,
    const float* __restrict__ bet, float* __restrict__ out) {
  constexpr int L     = (S == 0) ? 400 : 256;
  constexpr int START = (S == 0) ? 0 : (S == 1) ? 400 : 15760;
  constexpr int KK    = (S == 0) ? 1 : (S == 1) ? 60 : 36;
  constexpr int OFF   = (S == 0) ? 0 : (S == 1) ? 1 : 61;

  __shared__ float xs[400];
  __shared__ float rs[4], rs2[4];

  int m = blockIdx.x;
  int bb = m / KK, jj = m - bb * KK;
  const float* xp = x + (size_t)bb * TOTAL_DIM + START + jj * L;
  for (int k = threadIdx.x; k < L; k += 256) xs[k] = xp[k];
  __syncthreads();

  float h[2];
#pragma unroll
  for (int i = 0; i < 2; ++i) {
    int col = threadIdx.x + i * 256;
    float acc = 0.f;
    for (int k = 0; k < L; ++k) acc += xs[k] * W[k * 512 + col];
    h[i] = fmaxf(acc + bias[col], 0.f);
  }

  float s = h[0] + h[1], s2 = h[0] * h[0] + h[1] * h[1];
#pragma unroll
  for (int msk = 1; msk < 64; msk <<= 1) {
    s  += __shfl_xor(s, msk, 64);
    s2 += __shfl_xor(s2, msk, 64);
  }
  int wave = threadIdx.x >> 6, lane = threadIdx.x & 63;
  if (lane == 0) { rs[wave] = s; rs2[wave] = s2; }
  __syncthreads();
  s  = rs[0] + rs[1] + rs[2] + rs[3];
  s2 = rs2[0] + rs2[1] + rs2[2] + rs2[3];
  float mu  = s * (1.f / 512.f);
  float var = s2 * (1.f / 512.f) - mu * mu;
  float sc  = rsqrtf(var + EPSLN);

  float* op = out + ((size_t)bb * N_ROWS + OFF + jj) * D_MODEL;
#pragma unroll
  for (int i = 0; i < 2; ++i) {
    int col = threadIdx.x + i * 256;
    op[col] = (h[i] - mu) * sc * gam[col] + bet[col];
  }
}

extern "C" void kernel_launch(void* const* d_in, const int* in_sizes, int n_in,
                              void* d_out, int out_size, void* d_ws, size_t ws_size,
                              hipStream_t stream) {
  const float* x  = (const float*)d_in[0];
  const float* W0 = (const float*)d_in[1];
  const float* b0 = (const float*)d_in[2];
  const float* g0 = (const float*)d_in[3];
  const float* e0 = (const float*)d_in[4];
  const float* W1 = (const float*)d_in[5];
  const float* b1 = (const float*)d_in[6];
  const float* g1 = (const float*)d_in[7];
  const float* e1 = (const float*)d_in[8];
  const float* W2 = (const float*)d_in[9];
  const float* b2 = (const float*)d_in[10];
  const float* g2 = (const float*)d_in[11];
  const float* e2 = (const float*)d_in[12];
  float* out = (float*)d_out;

  if (ws_size >= (size_t)WT_BYTES) {
    // fast path: bf16 MFMA, fused GEMM+bias+ReLU+LN, 512-thr blocks, 4/CU
    unsigned short* wt = (unsigned short*)d_ws;
    prep_wt<<<464, 256, 0, stream>>>(W0, W1, W2, wt);
    fused_kernel<<<NB0 + NB1 + NB2, 512, SMEM_FUSED, stream>>>(
        x, wt, b0, g0, e0, b1, g1, e1, b2, g2, e2, out);
  } else {
    // zero-workspace fp32 fallback (correct, slower)
    fallback_split<0><<<2048,   256, 0, stream>>>(x, W0, b0, g0, e0, out);
    fallback_split<1><<<122880, 256, 0, stream>>>(x, W1, b1, g1, e1, out);
    fallback_split<2><<<73728,  256, 0, stream>>>(x, W2, b2, g2, e2, out);
  }
}